// Round 8
// baseline (419.380 us; speedup 1.0000x reference)
//
#include <hip/hip_runtime.h>
#include <hip/hip_bf16.h>
#include <stdint.h>

#define HD 128
#define GD 64
#define OUTD 16
#define NR 16   // atomic privatization replicas

typedef unsigned short u16;
typedef __attribute__((ext_vector_type(8))) short short8;
typedef __attribute__((ext_vector_type(4))) float f32x4;

__device__ __forceinline__ float bf2f(u16 u) {
  union { uint32_t i; float f; } v; v.i = ((uint32_t)u) << 16; return v.f;
}
__device__ __forceinline__ u16 f2bf(float f) {
  union { __hip_bfloat16 h; u16 u; } v; v.h = __float2bfloat16(f); return v.u;
}

// ---------------------------------------------------------------- utilities
__global__ void zero_f_k(float* p, int n) {
  int i = blockIdx.x * 256 + threadIdx.x;
  if (i < n) p[i] = 0.f;
}
__global__ void zero_i_k(int* p, int n) {
  int i = blockIdx.x * 256 + threadIdx.x;
  if (i < n) p[i] = 0;
}

// Detect int64 vs int32 layout of edge_index.
__global__ void detect_k(const int* ei, int* flag) {
  if (threadIdx.x == 0 && blockIdx.x == 0) {
    int all0 = 1;
    for (int k = 1; k < 128; k += 2) all0 &= (ei[k] == 0);
    *flag = all0;
  }
}

// Pack edge_index -> eidx[e]={row,col}; batch -> b32.
__global__ void convert_idx_k(const int* ei, const int* bt, int2* eidx, int* b32,
                              int E, int N, const int* flag) {
  int i = blockIdx.x * 256 + threadIdx.x;
  int is64 = *flag;
  if (i < E) {
    int r = is64 ? ei[2 * i] : ei[i];
    int c = is64 ? ei[2 * (E + i)] : ei[E + i];
    r = (r < 0) ? 0 : (r >= N ? N - 1 : r);
    c = (c < 0) ? 0 : (c >= N ? N - 1 : c);
    eidx[i] = make_int2(r, c);
  }
  if (i < N) {
    int v = is64 ? bt[2 * i] : bt[i];
    b32[i] = (v < 0) ? 0 : (v >= GD ? GD - 1 : v);
  }
}

// privatized in-degree count: replica k = blockIdx % NR
__global__ void count_k(const int2* __restrict__ eidx, int* __restrict__ cntR,
                        int E, int N) {
  int e = blockIdx.x * 256 + threadIdx.x;
  if (e >= E) return;
  int k = blockIdx.x & (NR - 1);
  atomicAdd(&cntR[k * N + eidx[e].y], 1);
}

__global__ void reduce_cnt_k(const int* __restrict__ cntR, int* __restrict__ cnt, int N) {
  int n = blockIdx.x * 256 + threadIdx.x;
  if (n >= N) return;
  int s = 0;
#pragma unroll
  for (int k = 0; k < NR; ++k) s += cntR[k * N + n];
  cnt[n] = s;
}

// ---- 3-step exclusive scan of cnt[0..N) -> offs
__global__ void scan1_k(const int* __restrict__ cnt, int* __restrict__ offs,
                        int* __restrict__ bsum, int Np) {
  __shared__ int s[1024];
  int i = blockIdx.x * 1024 + threadIdx.x;
  int v = (i < Np) ? cnt[i] : 0;
  s[threadIdx.x] = v;
  __syncthreads();
  for (int off = 1; off < 1024; off <<= 1) {
    int t = (threadIdx.x >= off) ? s[threadIdx.x - off] : 0;
    __syncthreads();
    s[threadIdx.x] += t;
    __syncthreads();
  }
  if (i < Np) offs[i] = s[threadIdx.x] - v;
  if (threadIdx.x == 1023) bsum[blockIdx.x] = s[1023];
}
__global__ void scan2_k(int* bsum, int nb) {
  if (threadIdx.x == 0 && blockIdx.x == 0) {
    int sum = 0;
    for (int i = 0; i < nb; ++i) { int v = bsum[i]; bsum[i] = sum; sum += v; }
  }
}
__global__ void scan3_k(int* __restrict__ offs, const int* __restrict__ bsum,
                        int Np, int E) {
  int i = blockIdx.x * 256 + threadIdx.x;
  if (i < Np) offs[i] = offs[i] + bsum[i >> 10];
  if (i == 0) offs[Np] = E;
}

// per-replica cursors
__global__ void cursR_k(const int* __restrict__ offs, const int* __restrict__ cntR,
                        int* __restrict__ cursR, int N) {
  int n = blockIdx.x * 256 + threadIdx.x;
  if (n >= N) return;
  int run = offs[n];
#pragma unroll
  for (int k = 0; k < NR; ++k) { cursR[k * N + n] = run; run += cntR[k * N + n]; }
}

// fill CSC (sorted by destination col): csc[p] = {row, bits(|w|)} — one 8B store
__global__ void fill_k(const int2* __restrict__ eidx, const float* __restrict__ ea,
                       int* __restrict__ cursR, int2* __restrict__ csc, int E, int N) {
  int e = blockIdx.x * 256 + threadIdx.x;
  if (e >= E) return;
  int k = blockIdx.x & (NR - 1);
  int2 rc = eidx[e];
  float a = ea[e];
  float w = isnan(a) ? 0.f : fabsf(a);
  int p = atomicAdd(&cursR[k * N + rc.y], 1);
  csc[p] = make_int2(rc.x, __float_as_int(w));
}

// dinv[n] = rsqrt(sum of in-weights + 1)
__global__ void deg_k(const int* __restrict__ offs, const int2* __restrict__ csc,
                      float* __restrict__ dinv, int N) {
  int n = blockIdx.x * 256 + threadIdx.x;
  if (n >= N) return;
  int p = offs[n], pe = offs[n + 1];
  float s = 0.f;
  for (; p < pe; ++p) s += __int_as_float(csc[p].y);
  dinv[n] = rsqrtf(s + 1.0f);
}

// csc[p].y = bits( dinv[row]*w*dinv[col] )   (in place)
__global__ void normcsc_k(const int* __restrict__ offs, int2* __restrict__ csc,
                          const float* __restrict__ dinv, int N) {
  int n = blockIdx.x * 256 + threadIdx.x;
  if (n >= N) return;
  float dc = dinv[n];
  int p = offs[n], pe = offs[n + 1];
  for (; p < pe; ++p) {
    int2 v = csc[p];
    v.y = __float_as_int(dinv[v.x] * __int_as_float(v.y) * dc);
    csc[p] = v;
  }
}

// h0 = concat(nan_to_num(x), isnan(x))  [N,128] bf16
__global__ void build_h0_k(const float* __restrict__ x, u16* __restrict__ A, int N) {
  int i = blockIdx.x * 256 + threadIdx.x;
  if (i >= N * HD) return;
  int n = i >> 7, f = i & 127;
  float v;
  if (f < 64) { float u = x[n * 64 + f];      v = isnan(u) ? 0.f : u; }
  else        { float u = x[n * 64 + f - 64]; v = isnan(u) ? 1.f : 0.f; }
  A[i] = f2bf(v);
}

// transpose+convert weights: Wt[n][k] = bf16(W[k][n])   (128x128)
__global__ void convw_k(const float* __restrict__ W, u16* __restrict__ Wt) {
  int i = blockIdx.x * 256 + threadIdx.x;
  if (i >= HD * HD) return;
  int n = i >> 7, k = i & 127;
  Wt[i] = f2bf(W[k * HD + n]);
}

// B[N,128] = A[N,128] @ W[128,128]  via MFMA 16x16x32 bf16, fp32 accum.
__global__ __launch_bounds__(256)
void gemm_k(const u16* __restrict__ A, const u16* __restrict__ Wt,
            u16* __restrict__ B, int N) {
  __shared__ u16 sw[128 * 136];
  const int t = threadIdx.x;
  {
    const uint32_t* src = (const uint32_t*)Wt;
    uint32_t* dst = (uint32_t*)sw;
#pragma unroll
    for (int k = 0; k < 32; ++k) {
      int q = t + k * 256;
      int r = q >> 6;
      int u = q & 63;
      dst[r * 68 + u] = src[r * 64 + u];
    }
  }
  __syncthreads();
  const int w = t >> 6;
  const int lane = t & 63;
  const int m = lane & 15;
  const int qd = lane >> 4;
  const int arow = blockIdx.x * 64 + w * 16 + m;
  short8 afr[4];
  if (arow < N) {
    const short8* ap = (const short8*)(A + (size_t)arow * HD);
#pragma unroll
    for (int s = 0; s < 4; ++s) afr[s] = ap[4 * s + qd];
  } else {
    short8 z = {0, 0, 0, 0, 0, 0, 0, 0};
#pragma unroll
    for (int s = 0; s < 4; ++s) afr[s] = z;
  }
  const int orow = blockIdx.x * 64 + w * 16 + qd * 4;
#pragma unroll
  for (int c = 0; c < 8; ++c) {
    f32x4 acc = {0.f, 0.f, 0.f, 0.f};
    const int n = c * 16 + m;
#pragma unroll
    for (int s = 0; s < 4; ++s) {
      short8 bfr = *(const short8*)(sw + n * 136 + 32 * s + 8 * qd);
      acc = __builtin_amdgcn_mfma_f32_16x16x32_bf16(afr[s], bfr, acc, 0, 0, 0);
    }
#pragma unroll
    for (int r = 0; r < 4; ++r) {
      int rr = orow + r;
      if (rr < N) B[(size_t)rr * HD + n] = f2bf(acc[r]);
    }
  }
}

// Fused: A[n] = BN?ReLU( dinv[n]^2*B[n] + bias + sum_in norm*B[row] )
__global__ __launch_bounds__(256)
void aggregate_k(const int* __restrict__ offs, const int2* __restrict__ csc,
                 const u16* __restrict__ B, const float* __restrict__ dinv,
                 const float* __restrict__ bias, const float* __restrict__ gamma,
                 const float* __restrict__ beta, const float* __restrict__ mean,
                 const float* __restrict__ var, int do_bn,
                 u16* __restrict__ A, int N) {
  int tid = blockIdx.x * 256 + threadIdx.x;
  int n = tid >> 5;
  if (n >= N) return;
  int f4 = (tid & 31) << 2;
  float d = dinv[n];
  ushort4 bu = *(const ushort4*)(B + (size_t)n * HD + f4);
  float ax = d * d * bf2f(bu.x) + bias[f4 + 0];
  float ay = d * d * bf2f(bu.y) + bias[f4 + 1];
  float az = d * d * bf2f(bu.z) + bias[f4 + 2];
  float aw = d * d * bf2f(bu.w) + bias[f4 + 3];

  int p = offs[n], pe = offs[n + 1];
  for (; p + 1 < pe; p += 2) {
    int2 e0 = csc[p], e1 = csc[p + 1];
    float w0 = __int_as_float(e0.y), w1 = __int_as_float(e1.y);
    ushort4 h0 = *(const ushort4*)(B + (size_t)e0.x * HD + f4);
    ushort4 h1 = *(const ushort4*)(B + (size_t)e1.x * HD + f4);
    ax += w0 * bf2f(h0.x) + w1 * bf2f(h1.x);
    ay += w0 * bf2f(h0.y) + w1 * bf2f(h1.y);
    az += w0 * bf2f(h0.z) + w1 * bf2f(h1.z);
    aw += w0 * bf2f(h0.w) + w1 * bf2f(h1.w);
  }
  if (p < pe) {
    int2 e0 = csc[p];
    float w0 = __int_as_float(e0.y);
    ushort4 h0 = *(const ushort4*)(B + (size_t)e0.x * HD + f4);
    ax += w0 * bf2f(h0.x); ay += w0 * bf2f(h0.y);
    az += w0 * bf2f(h0.z); aw += w0 * bf2f(h0.w);
  }
  if (do_bn) {
    float s0 = gamma[f4 + 0] * rsqrtf(var[f4 + 0] + 1e-5f);
    float s1 = gamma[f4 + 1] * rsqrtf(var[f4 + 1] + 1e-5f);
    float s2 = gamma[f4 + 2] * rsqrtf(var[f4 + 2] + 1e-5f);
    float s3 = gamma[f4 + 3] * rsqrtf(var[f4 + 3] + 1e-5f);
    ax = (ax - mean[f4 + 0]) * s0 + beta[f4 + 0];
    ay = (ay - mean[f4 + 1]) * s1 + beta[f4 + 1];
    az = (az - mean[f4 + 2]) * s2 + beta[f4 + 2];
    aw = (aw - mean[f4 + 3]) * s3 + beta[f4 + 3];
    ax = ax > 0.f ? ax : 0.f;
    ay = ay > 0.f ? ay : 0.f;
    az = az > 0.f ? az : 0.f;
    aw = aw > 0.f ? aw : 0.f;
  }
  ushort4 o;
  o.x = f2bf(ax); o.y = f2bf(ay); o.z = f2bf(az); o.w = f2bf(aw);
  *(ushort4*)(A + (size_t)n * HD + f4) = o;
}

// segment starts via binary search on sorted batch
__global__ void start_k(const int* __restrict__ b32, int* __restrict__ start, int N) {
  int b = threadIdx.x;
  if (b > GD) return;
  int lo = 0, hi = N;
  while (lo < hi) {
    int mid = (lo + hi) >> 1;
    if (b32[mid] < b) lo = mid + 1; else hi = mid;
  }
  start[b] = lo;
}

// two-stage mean pool, stage 1 (bf16 input)
__global__ __launch_bounds__(128)
void pool1_k(const u16* __restrict__ A, const int* __restrict__ start,
             float* __restrict__ sums) {
  int b = blockIdx.y;
  int s = start[b], e = start[b + 1];
  int len = e - s;
  if (len <= 0) return;
  int nch = gridDim.x;
  int ch = (len + nch - 1) / nch;
  int lo = s + blockIdx.x * ch;
  int hi = lo + ch; if (hi > e) hi = e;
  if (lo >= hi) return;
  int j = threadIdx.x;
  float a0 = 0.f, a1 = 0.f, a2 = 0.f, a3 = 0.f;
  int n = lo;
  for (; n + 3 < hi; n += 4) {
    a0 += bf2f(A[(size_t)(n + 0) * HD + j]);
    a1 += bf2f(A[(size_t)(n + 1) * HD + j]);
    a2 += bf2f(A[(size_t)(n + 2) * HD + j]);
    a3 += bf2f(A[(size_t)(n + 3) * HD + j]);
  }
  for (; n < hi; ++n) a0 += bf2f(A[(size_t)n * HD + j]);
  unsafeAtomicAdd(&sums[b * HD + j], (a0 + a1) + (a2 + a3));
}

// out = gelu((sums/cnt)@mW1+mb1) @ mW2 + mb2
__global__ __launch_bounds__(128)
void mlp_k(const float* __restrict__ sums, const int* __restrict__ start,
           const float* __restrict__ mW1, const float* __restrict__ mb1,
           const float* __restrict__ mW2, const float* __restrict__ mb2,
           float* __restrict__ out) {
  __shared__ float sg[128];
  __shared__ float st[128];
  int b = blockIdx.x, j = threadIdx.x;
  int cnt = start[b + 1] - start[b];
  float inv = 1.0f / (float)(cnt > 0 ? cnt : 1);
  sg[j] = sums[b * HD + j] * inv;
  __syncthreads();
  float s = mb1[j];
#pragma unroll 4
  for (int i = 0; i < 128; ++i) s += sg[i] * mW1[i * 128 + j];
  float ge = 0.5f * s * (1.0f + erff(s * 0.70710678118654752f));
  st[j] = ge;
  __syncthreads();
  if (j < OUTD) {
    float o = mb2[j];
#pragma unroll 4
    for (int k = 0; k < 128; ++k) o += st[k] * mW2[k * OUTD + j];
    out[b * OUTD + j] = o;
  }
}

// ---------------------------------------------------------------- launch
extern "C" void kernel_launch(void* const* d_in, const int* in_sizes, int n_in,
                              void* d_out, int out_size, void* d_ws, size_t ws_size,
                              hipStream_t stream) {
  const float* x   = (const float*)d_in[0];
  const int* ei    = (const int*)d_in[1];
  const float* ea  = (const float*)d_in[2];
  const int* bt    = (const int*)d_in[3];
  const float* W0  = (const float*)d_in[4];
  const float* b0  = (const float*)d_in[5];
  const float* W1  = (const float*)d_in[6];
  const float* b1  = (const float*)d_in[7];
  const float* W2  = (const float*)d_in[8];
  const float* b2  = (const float*)d_in[9];
  const float* bng = (const float*)d_in[10];
  const float* bnb = (const float*)d_in[11];
  const float* bnm = (const float*)d_in[12];
  const float* bnv = (const float*)d_in[13];
  const float* mW1 = (const float*)d_in[14];
  const float* mb1 = (const float*)d_in[15];
  const float* mW2 = (const float*)d_in[16];
  const float* mb2 = (const float*)d_in[17];
  float* out = (float*)d_out;

  const int N = in_sizes[0] / 64;      // 50000
  const int E = in_sizes[2];           // 800000

  char* ws = (char*)d_ws;
  size_t NB2 = (size_t)N * HD * 2;     // bf16 feature buffer
  u16* A       = (u16*)(ws);
  u16* B       = (u16*)(ws + NB2);
  char* q      = ws + 2 * NB2;
  u16* Wt0     = (u16*)q;              q += (size_t)HD * HD * 2;
  u16* Wt1     = (u16*)q;              q += (size_t)HD * HD * 2;
  u16* Wt2     = (u16*)q;              q += (size_t)HD * HD * 2;
  int2* csc    = (int2*)q;             q += (size_t)E * 8;
  int2* eidx   = (int2*)q;             q += (size_t)E * 8;
  float* dinv  = (float*)q;            q += (size_t)N * 4;
  int*   cntR  = (int*)q;              q += (size_t)NR * N * 4;
  int*   cursR = (int*)q;              q += (size_t)NR * N * 4;
  int*   cnt   = (int*)q;              q += (size_t)N * 4;
  int*   offs  = (int*)q;              q += (size_t)(N + 2) * 4;
  int*   b32   = (int*)q;              q += (size_t)N * 4;
  int*   bsum  = (int*)q;              q += 64 * 4;
  float* sums  = (float*)q;            q += GD * HD * 4;
  int*   strt  = (int*)q;              q += 68 * 4;
  int*   flag  = (int*)q;

  const int NH = N * HD;
  dim3 blk(256);
  int gNH = (NH + 255) / 256;
  int gE  = (E + 255) / 256;
  int gN  = (N + 255) / 256;
  int gW  = (HD * HD + 255) / 256;
  int nb1024 = (N + 1023) / 1024;

  detect_k<<<1, 64, 0, stream>>>(ei, flag);
  convert_idx_k<<<gE, blk, 0, stream>>>(ei, bt, eidx, b32, E, N, flag);
  zero_i_k<<<(NR * N + 255) / 256, blk, 0, stream>>>(cntR, NR * N);
  zero_f_k<<<(GD * HD + 255) / 256, blk, 0, stream>>>(sums, GD * HD);
  convw_k<<<gW, blk, 0, stream>>>(W0, Wt0);
  convw_k<<<gW, blk, 0, stream>>>(W1, Wt1);
  convw_k<<<gW, blk, 0, stream>>>(W2, Wt2);
  count_k<<<gE, blk, 0, stream>>>(eidx, cntR, E, N);
  reduce_cnt_k<<<gN, blk, 0, stream>>>(cntR, cnt, N);
  scan1_k<<<nb1024, 1024, 0, stream>>>(cnt, offs, bsum, N);
  scan2_k<<<1, 64, 0, stream>>>(bsum, nb1024);
  scan3_k<<<gN, blk, 0, stream>>>(offs, bsum, N, E);
  cursR_k<<<gN, blk, 0, stream>>>(offs, cntR, cursR, N);
  fill_k<<<gE, blk, 0, stream>>>(eidx, ea, cursR, csc, E, N);
  deg_k<<<gN, blk, 0, stream>>>(offs, csc, dinv, N);
  normcsc_k<<<gN, blk, 0, stream>>>(offs, csc, dinv, N);
  build_h0_k<<<gNH, blk, 0, stream>>>(x, A, N);

  int gGemm = (N + 63) / 64;
  int gAgg  = (N * 32 + 255) / 256;

  // layer 0
  gemm_k<<<gGemm, 256, 0, stream>>>(A, Wt0, B, N);
  aggregate_k<<<gAgg, blk, 0, stream>>>(offs, csc, B, dinv, b0,
                                        bng, bnb, bnm, bnv, 1, A, N);
  // layer 1
  gemm_k<<<gGemm, 256, 0, stream>>>(A, Wt1, B, N);
  aggregate_k<<<gAgg, blk, 0, stream>>>(offs, csc, B, dinv, b1,
                                        bng, bnb, bnm, bnv, 1, A, N);
  // layer 2 (no bn/relu)
  gemm_k<<<gGemm, 256, 0, stream>>>(A, Wt2, B, N);
  aggregate_k<<<gAgg, blk, 0, stream>>>(offs, csc, B, dinv, b2,
                                        bng, bnb, bnm, bnv, 0, A, N);

  start_k<<<1, 128, 0, stream>>>(b32, strt, N);
  dim3 pgrid(16, GD);
  pool1_k<<<pgrid, 128, 0, stream>>>(A, strt, sums);
  mlp_k<<<GD, 128, 0, stream>>>(sums, strt, mW1, mb1, mW2, mb2, out);
}

// Round 9
// 379.299 us; speedup vs baseline: 1.1057x; 1.1057x over previous
//
#include <hip/hip_runtime.h>
#include <hip/hip_bf16.h>
#include <stdint.h>

#define HD 128
#define GD 64
#define OUTD 16
#define NR 16   // atomic privatization replicas

typedef unsigned short u16;
typedef __attribute__((ext_vector_type(8))) short short8;
typedef __attribute__((ext_vector_type(4))) float f32x4;

__device__ __forceinline__ float bf2f(u16 u) {
  union { uint32_t i; float f; } v; v.i = ((uint32_t)u) << 16; return v.f;
}
__device__ __forceinline__ u16 f2bf(float f) {
  union { __hip_bfloat16 h; u16 u; } v; v.h = __float2bfloat16(f); return v.u;
}

// Fused: layout-detect + index convert + batch convert + privatized count
// producing per-edge rank.  k = blockIdx & (NR-1); fill_k MUST use same mapping.
__global__ __launch_bounds__(256)
void convert_count_k(const int* __restrict__ ei, const int* __restrict__ bt,
                     int2* __restrict__ eidx, int* __restrict__ b32,
                     int* __restrict__ cntR, int* __restrict__ rank,
                     int E, int N) {
  __shared__ int s_is64;
  if (threadIdx.x == 0) {
    int all0 = 1;
    for (int k = 1; k < 128; k += 2) all0 &= (ei[k] == 0);
    s_is64 = all0;
  }
  __syncthreads();
  int is64 = s_is64;
  int i = blockIdx.x * 256 + threadIdx.x;
  if (i < E) {
    int r = is64 ? ei[2 * i] : ei[i];
    int c = is64 ? ei[2 * (E + i)] : ei[E + i];
    r = (r < 0) ? 0 : (r >= N ? N - 1 : r);
    c = (c < 0) ? 0 : (c >= N ? N - 1 : c);
    eidx[i] = make_int2(r, c);
    int k = blockIdx.x & (NR - 1);
    rank[i] = atomicAdd(&cntR[k * N + c], 1);
  }
  if (i < N) {
    int v = is64 ? bt[2 * i] : bt[i];
    b32[i] = (v < 0) ? 0 : (v >= GD ? GD - 1 : v);
  }
}

// ---- 3-step exclusive scan; scan1 sums the NR replicas inline
__global__ void scan1_k(const int* __restrict__ cntR, int* __restrict__ offs,
                        int* __restrict__ bsum, int Np, int N) {
  __shared__ int s[1024];
  int i = blockIdx.x * 1024 + threadIdx.x;
  int v = 0;
  if (i < Np) {
#pragma unroll
    for (int k = 0; k < NR; ++k) v += cntR[k * N + i];
  }
  s[threadIdx.x] = v;
  __syncthreads();
  for (int off = 1; off < 1024; off <<= 1) {
    int t = (threadIdx.x >= off) ? s[threadIdx.x - off] : 0;
    __syncthreads();
    s[threadIdx.x] += t;
    __syncthreads();
  }
  if (i < Np) offs[i] = s[threadIdx.x] - v;
  if (threadIdx.x == 1023) bsum[blockIdx.x] = s[1023];
}
__global__ void scan2_k(int* bsum, int nb) {
  if (threadIdx.x == 0 && blockIdx.x == 0) {
    int sum = 0;
    for (int i = 0; i < nb; ++i) { int v = bsum[i]; bsum[i] = sum; sum += v; }
  }
}
__global__ void scan3_k(int* __restrict__ offs, const int* __restrict__ bsum,
                        int Np, int E) {
  int i = blockIdx.x * 256 + threadIdx.x;
  if (i < Np) offs[i] = offs[i] + bsum[i >> 10];
  if (i == 0) offs[Np] = E;
}

// per-replica cursor bases
__global__ void cursR_k(const int* __restrict__ offs, const int* __restrict__ cntR,
                        int* __restrict__ cursR, int N) {
  int n = blockIdx.x * 256 + threadIdx.x;
  if (n >= N) return;
  int run = offs[n];
#pragma unroll
  for (int k = 0; k < NR; ++k) { cursR[k * N + n] = run; run += cntR[k * N + n]; }
}

// fill CSC — ATOMIC-FREE: p = cursR[k][col] + rank[e]; one 8B scattered store.
__global__ __launch_bounds__(256)
void fill_k(const int2* __restrict__ eidx, const float* __restrict__ ea,
            const int* __restrict__ cursR, const int* __restrict__ rank,
            int2* __restrict__ csc, int E, int N) {
  int e = blockIdx.x * 256 + threadIdx.x;
  if (e >= E) return;
  int k = blockIdx.x & (NR - 1);
  int2 rc = eidx[e];
  float a = ea[e];
  float w = isnan(a) ? 0.f : fabsf(a);
  int p = cursR[k * N + rc.y] + rank[e];
  csc[p] = make_int2(rc.x, __float_as_int(w));
}

// dinv[n] = rsqrt(sum of in-weights + 1)
__global__ void deg_k(const int* __restrict__ offs, const int2* __restrict__ csc,
                      float* __restrict__ dinv, int N) {
  int n = blockIdx.x * 256 + threadIdx.x;
  if (n >= N) return;
  int p = offs[n], pe = offs[n + 1];
  float s = 0.f;
  for (; p < pe; ++p) s += __int_as_float(csc[p].y);
  dinv[n] = rsqrtf(s + 1.0f);
}

// csc[p].y = bits( dinv[row]*w*dinv[col] )   (in place)
__global__ void normcsc_k(const int* __restrict__ offs, int2* __restrict__ csc,
                          const float* __restrict__ dinv, int N) {
  int n = blockIdx.x * 256 + threadIdx.x;
  if (n >= N) return;
  float dc = dinv[n];
  int p = offs[n], pe = offs[n + 1];
  for (; p < pe; ++p) {
    int2 v = csc[p];
    v.y = __float_as_int(dinv[v.x] * __int_as_float(v.y) * dc);
    csc[p] = v;
  }
}

// h0 = concat(nan_to_num(x), isnan(x))  [N,128] bf16
__global__ void build_h0_k(const float* __restrict__ x, u16* __restrict__ A, int N) {
  int i = blockIdx.x * 256 + threadIdx.x;
  if (i >= N * HD) return;
  int n = i >> 7, f = i & 127;
  float v;
  if (f < 64) { float u = x[n * 64 + f];      v = isnan(u) ? 0.f : u; }
  else        { float u = x[n * 64 + f - 64]; v = isnan(u) ? 1.f : 0.f; }
  A[i] = f2bf(v);
}

// transpose+convert all 3 weights: Wt[l][n][k] = bf16(W_l[k][n])
__global__ void convw3_k(const float* __restrict__ W0, const float* __restrict__ W1,
                         const float* __restrict__ W2, u16* __restrict__ Wt) {
  int i = blockIdx.x * 256 + threadIdx.x;
  if (i >= 3 * HD * HD) return;
  int l = i / (HD * HD);
  int r = i - l * (HD * HD);
  int n = r >> 7, k = r & 127;
  const float* W = (l == 0) ? W0 : (l == 1) ? W1 : W2;
  Wt[i] = f2bf(W[k * HD + n]);
}

// B[N,128] = A[N,128] @ W[128,128]  via MFMA 16x16x32 bf16, fp32 accum.
__global__ __launch_bounds__(256)
void gemm_k(const u16* __restrict__ A, const u16* __restrict__ Wt,
            u16* __restrict__ B, int N) {
  __shared__ u16 sw[128 * 136];
  const int t = threadIdx.x;
  {
    const uint32_t* src = (const uint32_t*)Wt;
    uint32_t* dst = (uint32_t*)sw;
#pragma unroll
    for (int k = 0; k < 32; ++k) {
      int q = t + k * 256;
      int r = q >> 6;
      int u = q & 63;
      dst[r * 68 + u] = src[r * 64 + u];
    }
  }
  __syncthreads();
  const int w = t >> 6;
  const int lane = t & 63;
  const int m = lane & 15;
  const int qd = lane >> 4;
  const int arow = blockIdx.x * 64 + w * 16 + m;
  short8 afr[4];
  if (arow < N) {
    const short8* ap = (const short8*)(A + (size_t)arow * HD);
#pragma unroll
    for (int s = 0; s < 4; ++s) afr[s] = ap[4 * s + qd];
  } else {
    short8 z = {0, 0, 0, 0, 0, 0, 0, 0};
#pragma unroll
    for (int s = 0; s < 4; ++s) afr[s] = z;
  }
  const int orow = blockIdx.x * 64 + w * 16 + qd * 4;
#pragma unroll
  for (int c = 0; c < 8; ++c) {
    f32x4 acc = {0.f, 0.f, 0.f, 0.f};
    const int n = c * 16 + m;
#pragma unroll
    for (int s = 0; s < 4; ++s) {
      short8 bfr = *(const short8*)(sw + n * 136 + 32 * s + 8 * qd);
      acc = __builtin_amdgcn_mfma_f32_16x16x32_bf16(afr[s], bfr, acc, 0, 0, 0);
    }
#pragma unroll
    for (int r = 0; r < 4; ++r) {
      int rr = orow + r;
      if (rr < N) B[(size_t)rr * HD + n] = f2bf(acc[r]);
    }
  }
}

// Fused: A[n] = BN?ReLU( dinv[n]^2*B[n] + bias + sum_in norm*B[row] )
__global__ __launch_bounds__(256)
void aggregate_k(const int* __restrict__ offs, const int2* __restrict__ csc,
                 const u16* __restrict__ B, const float* __restrict__ dinv,
                 const float* __restrict__ bias, const float* __restrict__ gamma,
                 const float* __restrict__ beta, const float* __restrict__ mean,
                 const float* __restrict__ var, int do_bn,
                 u16* __restrict__ A, int N) {
  int tid = blockIdx.x * 256 + threadIdx.x;
  int n = tid >> 5;
  if (n >= N) return;
  int f4 = (tid & 31) << 2;
  float d = dinv[n];
  ushort4 bu = *(const ushort4*)(B + (size_t)n * HD + f4);
  float ax = d * d * bf2f(bu.x) + bias[f4 + 0];
  float ay = d * d * bf2f(bu.y) + bias[f4 + 1];
  float az = d * d * bf2f(bu.z) + bias[f4 + 2];
  float aw = d * d * bf2f(bu.w) + bias[f4 + 3];

  int p = offs[n], pe = offs[n + 1];
  for (; p + 1 < pe; p += 2) {
    int2 e0 = csc[p], e1 = csc[p + 1];
    float w0 = __int_as_float(e0.y), w1 = __int_as_float(e1.y);
    ushort4 h0 = *(const ushort4*)(B + (size_t)e0.x * HD + f4);
    ushort4 h1 = *(const ushort4*)(B + (size_t)e1.x * HD + f4);
    ax += w0 * bf2f(h0.x) + w1 * bf2f(h1.x);
    ay += w0 * bf2f(h0.y) + w1 * bf2f(h1.y);
    az += w0 * bf2f(h0.z) + w1 * bf2f(h1.z);
    aw += w0 * bf2f(h0.w) + w1 * bf2f(h1.w);
  }
  if (p < pe) {
    int2 e0 = csc[p];
    float w0 = __int_as_float(e0.y);
    ushort4 h0 = *(const ushort4*)(B + (size_t)e0.x * HD + f4);
    ax += w0 * bf2f(h0.x); ay += w0 * bf2f(h0.y);
    az += w0 * bf2f(h0.z); aw += w0 * bf2f(h0.w);
  }
  if (do_bn) {
    float s0 = gamma[f4 + 0] * rsqrtf(var[f4 + 0] + 1e-5f);
    float s1 = gamma[f4 + 1] * rsqrtf(var[f4 + 1] + 1e-5f);
    float s2 = gamma[f4 + 2] * rsqrtf(var[f4 + 2] + 1e-5f);
    float s3 = gamma[f4 + 3] * rsqrtf(var[f4 + 3] + 1e-5f);
    ax = (ax - mean[f4 + 0]) * s0 + beta[f4 + 0];
    ay = (ay - mean[f4 + 1]) * s1 + beta[f4 + 1];
    az = (az - mean[f4 + 2]) * s2 + beta[f4 + 2];
    aw = (aw - mean[f4 + 3]) * s3 + beta[f4 + 3];
    ax = ax > 0.f ? ax : 0.f;
    ay = ay > 0.f ? ay : 0.f;
    az = az > 0.f ? az : 0.f;
    aw = aw > 0.f ? aw : 0.f;
  }
  ushort4 o;
  o.x = f2bf(ax); o.y = f2bf(ay); o.z = f2bf(az); o.w = f2bf(aw);
  *(ushort4*)(A + (size_t)n * HD + f4) = o;
}

__device__ __forceinline__ int seg_lower_bound(const int* b32, int N, int b) {
  int lo = 0, hi = N;
  while (lo < hi) {
    int mid = (lo + hi) >> 1;
    if (b32[mid] < b) lo = mid + 1; else hi = mid;
  }
  return lo;
}

// two-stage mean pool, stage 1 (bf16 input); segment bounds found inline
__global__ __launch_bounds__(128)
void pool1_k(const u16* __restrict__ A, const int* __restrict__ b32,
             float* __restrict__ sums, int N) {
  __shared__ int sb[2];
  int b = blockIdx.y;
  if (threadIdx.x == 0) sb[0] = seg_lower_bound(b32, N, b);
  if (threadIdx.x == 1) sb[1] = seg_lower_bound(b32, N, b + 1);
  __syncthreads();
  int s = sb[0], e = sb[1];
  int len = e - s;
  if (len <= 0) return;
  int nch = gridDim.x;
  int ch = (len + nch - 1) / nch;
  int lo = s + blockIdx.x * ch;
  int hi = lo + ch; if (hi > e) hi = e;
  if (lo >= hi) return;
  int j = threadIdx.x;
  float a0 = 0.f, a1 = 0.f, a2 = 0.f, a3 = 0.f;
  int n = lo;
  for (; n + 3 < hi; n += 4) {
    a0 += bf2f(A[(size_t)(n + 0) * HD + j]);
    a1 += bf2f(A[(size_t)(n + 1) * HD + j]);
    a2 += bf2f(A[(size_t)(n + 2) * HD + j]);
    a3 += bf2f(A[(size_t)(n + 3) * HD + j]);
  }
  for (; n < hi; ++n) a0 += bf2f(A[(size_t)n * HD + j]);
  unsafeAtomicAdd(&sums[b * HD + j], (a0 + a1) + (a2 + a3));
}

// out = gelu((sums/cnt)@mW1+mb1) @ mW2 + mb2
__global__ __launch_bounds__(128)
void mlp_k(const float* __restrict__ sums, const int* __restrict__ b32,
           const float* __restrict__ mW1, const float* __restrict__ mb1,
           const float* __restrict__ mW2, const float* __restrict__ mb2,
           float* __restrict__ out, int N) {
  __shared__ float sg[128];
  __shared__ float st[128];
  __shared__ int sb[2];
  int b = blockIdx.x, j = threadIdx.x;
  if (j == 0) sb[0] = seg_lower_bound(b32, N, b);
  if (j == 1) sb[1] = seg_lower_bound(b32, N, b + 1);
  __syncthreads();
  int cnt = sb[1] - sb[0];
  float inv = 1.0f / (float)(cnt > 0 ? cnt : 1);
  sg[j] = sums[b * HD + j] * inv;
  __syncthreads();
  float s = mb1[j];
#pragma unroll 4
  for (int i = 0; i < 128; ++i) s += sg[i] * mW1[i * 128 + j];
  float ge = 0.5f * s * (1.0f + erff(s * 0.70710678118654752f));
  st[j] = ge;
  __syncthreads();
  if (j < OUTD) {
    float o = mb2[j];
#pragma unroll 4
    for (int k = 0; k < 128; ++k) o += st[k] * mW2[k * OUTD + j];
    out[b * OUTD + j] = o;
  }
}

// ---------------------------------------------------------------- launch
extern "C" void kernel_launch(void* const* d_in, const int* in_sizes, int n_in,
                              void* d_out, int out_size, void* d_ws, size_t ws_size,
                              hipStream_t stream) {
  const float* x   = (const float*)d_in[0];
  const int* ei    = (const int*)d_in[1];
  const float* ea  = (const float*)d_in[2];
  const int* bt    = (const int*)d_in[3];
  const float* W0  = (const float*)d_in[4];
  const float* b0  = (const float*)d_in[5];
  const float* W1  = (const float*)d_in[6];
  const float* b1  = (const float*)d_in[7];
  const float* W2  = (const float*)d_in[8];
  const float* b2  = (const float*)d_in[9];
  const float* bng = (const float*)d_in[10];
  const float* bnb = (const float*)d_in[11];
  const float* bnm = (const float*)d_in[12];
  const float* bnv = (const float*)d_in[13];
  const float* mW1 = (const float*)d_in[14];
  const float* mb1 = (const float*)d_in[15];
  const float* mW2 = (const float*)d_in[16];
  const float* mb2 = (const float*)d_in[17];
  float* out = (float*)d_out;

  const int N = in_sizes[0] / 64;      // 50000
  const int E = in_sizes[2];           // 800000

  char* ws = (char*)d_ws;
  size_t NB2 = (size_t)N * HD * 2;     // bf16 feature buffer
  u16* A       = (u16*)(ws);
  u16* B       = (u16*)(ws + NB2);
  char* q      = ws + 2 * NB2;
  u16* Wt      = (u16*)q;              q += (size_t)3 * HD * HD * 2;
  int2* csc    = (int2*)q;             q += (size_t)E * 8;
  int2* eidx   = (int2*)q;             q += (size_t)E * 8;
  int*  rank   = (int*)q;              q += (size_t)E * 4;
  float* dinv  = (float*)q;            q += (size_t)N * 4;
  int*   cntR  = (int*)q;              q += (size_t)NR * N * 4;
  int*   cursR = (int*)q;              q += (size_t)NR * N * 4;
  int*   offs  = (int*)q;              q += (size_t)(N + 2) * 4;
  int*   b32   = (int*)q;              q += (size_t)N * 4;
  int*   bsum  = (int*)q;              q += 64 * 4;
  float* sums  = (float*)q;            q += GD * HD * 4;

  const int NH = N * HD;
  dim3 blk(256);
  int gNH = (NH + 255) / 256;
  int gE  = (E + 255) / 256;
  int gN  = (N + 255) / 256;
  int nb1024 = (N + 1023) / 1024;

  hipMemsetAsync(cntR, 0, (size_t)NR * N * 4, stream);
  hipMemsetAsync(sums, 0, (size_t)GD * HD * 4, stream);
  convert_count_k<<<gE, blk, 0, stream>>>(ei, bt, eidx, b32, cntR, rank, E, N);
  scan1_k<<<nb1024, 1024, 0, stream>>>(cntR, offs, bsum, N, N);
  scan2_k<<<1, 64, 0, stream>>>(bsum, nb1024);
  scan3_k<<<gN, blk, 0, stream>>>(offs, bsum, N, E);
  cursR_k<<<gN, blk, 0, stream>>>(offs, cntR, cursR, N);
  fill_k<<<gE, blk, 0, stream>>>(eidx, ea, cursR, rank, csc, E, N);
  deg_k<<<gN, blk, 0, stream>>>(offs, csc, dinv, N);
  normcsc_k<<<gN, blk, 0, stream>>>(offs, csc, dinv, N);
  build_h0_k<<<gNH, blk, 0, stream>>>(x, A, N);
  convw3_k<<<(3 * HD * HD + 255) / 256, blk, 0, stream>>>(W0, W1, W2, Wt);

  int gGemm = (N + 63) / 64;
  int gAgg  = (N * 32 + 255) / 256;

  // layer 0
  gemm_k<<<gGemm, 256, 0, stream>>>(A, Wt, B, N);
  aggregate_k<<<gAgg, blk, 0, stream>>>(offs, csc, B, dinv, b0,
                                        bng, bnb, bnm, bnv, 1, A, N);
  // layer 1
  gemm_k<<<gGemm, 256, 0, stream>>>(A, Wt + HD * HD, B, N);
  aggregate_k<<<gAgg, blk, 0, stream>>>(offs, csc, B, dinv, b1,
                                        bng, bnb, bnm, bnv, 1, A, N);
  // layer 2 (no bn/relu)
  gemm_k<<<gGemm, 256, 0, stream>>>(A, Wt + 2 * HD * HD, B, N);
  aggregate_k<<<gAgg, blk, 0, stream>>>(offs, csc, B, dinv, b2,
                                        bng, bnb, bnm, bnv, 0, A, N);

  dim3 pgrid(16, GD);
  pool1_k<<<pgrid, 128, 0, stream>>>(A, b32, sums, N);
  mlp_k<<<GD, 128, 0, stream>>>(sums, b32, mW1, mb1, mW2, mb2, out, N);
}

// Round 10
// 337.920 us; speedup vs baseline: 1.2411x; 1.1225x over previous
//
#include <hip/hip_runtime.h>
#include <hip/hip_bf16.h>
#include <stdint.h>

#define HD 128
#define GD 64
#define OUTD 16
#define NR 16   // atomic privatization replicas

typedef unsigned short u16;
typedef __attribute__((ext_vector_type(8))) short short8;
typedef __attribute__((ext_vector_type(4))) float f32x4;

__device__ __forceinline__ float bf2f(u16 u) {
  union { uint32_t i; float f; } v; v.i = ((uint32_t)u) << 16; return v.f;
}
__device__ __forceinline__ u16 f2bf(float f) {
  union { __hip_bfloat16 h; u16 u; } v; v.h = __float2bfloat16(f); return v.u;
}

// Fused: layout-detect + index convert + batch convert + privatized count
// producing per-edge rank.  k = blockIdx & (NR-1); fill_k MUST use same mapping.
__global__ __launch_bounds__(256)
void convert_count_k(const int* __restrict__ ei, const int* __restrict__ bt,
                     int2* __restrict__ eidx, int* __restrict__ b32,
                     int* __restrict__ cntR, int* __restrict__ rank,
                     int E, int N) {
  __shared__ int s_is64;
  if (threadIdx.x == 0) {
    int all0 = 1;
    for (int k = 1; k < 128; k += 2) all0 &= (ei[k] == 0);
    s_is64 = all0;
  }
  __syncthreads();
  int is64 = s_is64;
  int i = blockIdx.x * 256 + threadIdx.x;
  if (i < E) {
    int r = is64 ? ei[2 * i] : ei[i];
    int c = is64 ? ei[2 * (E + i)] : ei[E + i];
    r = (r < 0) ? 0 : (r >= N ? N - 1 : r);
    c = (c < 0) ? 0 : (c >= N ? N - 1 : c);
    eidx[i] = make_int2(r, c);
    int k = blockIdx.x & (NR - 1);
    rank[i] = atomicAdd(&cntR[k * N + c], 1);
  }
  if (i < N) {
    int v = is64 ? bt[2 * i] : bt[i];
    b32[i] = (v < 0) ? 0 : (v >= GD ? GD - 1 : v);
  }
}

// ---- 3-step exclusive scan; scan1 sums the NR replicas inline
__global__ void scan1_k(const int* __restrict__ cntR, int* __restrict__ offs,
                        int* __restrict__ bsum, int Np, int N) {
  __shared__ int s[1024];
  int i = blockIdx.x * 1024 + threadIdx.x;
  int v = 0;
  if (i < Np) {
#pragma unroll
    for (int k = 0; k < NR; ++k) v += cntR[k * N + i];
  }
  s[threadIdx.x] = v;
  __syncthreads();
  for (int off = 1; off < 1024; off <<= 1) {
    int t = (threadIdx.x >= off) ? s[threadIdx.x - off] : 0;
    __syncthreads();
    s[threadIdx.x] += t;
    __syncthreads();
  }
  if (i < Np) offs[i] = s[threadIdx.x] - v;
  if (threadIdx.x == 1023) bsum[blockIdx.x] = s[1023];
}
__global__ void scan2_k(int* bsum, int nb) {
  if (threadIdx.x == 0 && blockIdx.x == 0) {
    int sum = 0;
    for (int i = 0; i < nb; ++i) { int v = bsum[i]; bsum[i] = sum; sum += v; }
  }
}
__global__ void scan3_k(int* __restrict__ offs, const int* __restrict__ bsum,
                        int Np, int E) {
  int i = blockIdx.x * 256 + threadIdx.x;
  if (i < Np) offs[i] = offs[i] + bsum[i >> 10];
  if (i == 0) offs[Np] = E;
}

// per-replica cursor bases
__global__ void cursR_k(const int* __restrict__ offs, const int* __restrict__ cntR,
                        int* __restrict__ cursR, int N) {
  int n = blockIdx.x * 256 + threadIdx.x;
  if (n >= N) return;
  int run = offs[n];
#pragma unroll
  for (int k = 0; k < NR; ++k) { cursR[k * N + n] = run; run += cntR[k * N + n]; }
}

// fill CSC — atomic-free: p = cursR[k][col] + rank[e]; one 8B scattered store.
__global__ __launch_bounds__(256)
void fill_k(const int2* __restrict__ eidx, const float* __restrict__ ea,
            const int* __restrict__ cursR, const int* __restrict__ rank,
            int2* __restrict__ csc, int E, int N) {
  int e = blockIdx.x * 256 + threadIdx.x;
  if (e >= E) return;
  int k = blockIdx.x & (NR - 1);
  int2 rc = eidx[e];
  float a = ea[e];
  float w = isnan(a) ? 0.f : fabsf(a);
  int p = cursR[k * N + rc.y] + rank[e];
  csc[p] = make_int2(rc.x, __float_as_int(w));
}

// dinv[n] = rsqrt(sum of in-weights + 1)
__global__ void deg_k(const int* __restrict__ offs, const int2* __restrict__ csc,
                      float* __restrict__ dinv, int N) {
  int n = blockIdx.x * 256 + threadIdx.x;
  if (n >= N) return;
  int p = offs[n], pe = offs[n + 1];
  float s = 0.f;
  for (; p < pe; ++p) s += __int_as_float(csc[p].y);
  dinv[n] = rsqrtf(s + 1.0f);
}

// csc[p].y = bits( dinv[row]*w*dinv[col] )   (in place)
__global__ void normcsc_k(const int* __restrict__ offs, int2* __restrict__ csc,
                          const float* __restrict__ dinv, int N) {
  int n = blockIdx.x * 256 + threadIdx.x;
  if (n >= N) return;
  float dc = dinv[n];
  int p = offs[n], pe = offs[n + 1];
  for (; p < pe; ++p) {
    int2 v = csc[p];
    v.y = __float_as_int(dinv[v.x] * __int_as_float(v.y) * dc);
    csc[p] = v;
  }
}

// transpose+convert all 3 weights: Wt[l][n][k] = bf16(W_l[k][n])
__global__ void convw3_k(const float* __restrict__ W0, const float* __restrict__ W1,
                         const float* __restrict__ W2, u16* __restrict__ Wt) {
  int i = blockIdx.x * 256 + threadIdx.x;
  if (i >= 3 * HD * HD) return;
  int l = i / (HD * HD);
  int r = i - l * (HD * HD);
  int n = r >> 7, k = r & 127;
  const float* W = (l == 0) ? W0 : (l == 1) ? W1 : W2;
  Wt[i] = f2bf(W[k * HD + n]);
}

// ---- shared MFMA core: compute B-tile given afr fragments
__device__ __forceinline__ void gemm_core(const u16* sw, const short8* afr,
                                          int m, int qd, int orow,
                                          u16* __restrict__ B, int N) {
#pragma unroll
  for (int c = 0; c < 8; ++c) {
    f32x4 acc = {0.f, 0.f, 0.f, 0.f};
    const int n = c * 16 + m;
#pragma unroll
    for (int s = 0; s < 4; ++s) {
      short8 bfr = *(const short8*)(sw + n * 136 + 32 * s + 8 * qd);
      acc = __builtin_amdgcn_mfma_f32_16x16x32_bf16(afr[s], bfr, acc, 0, 0, 0);
    }
#pragma unroll
    for (int r = 0; r < 4; ++r) {
      int rr = orow + r;
      if (rr < N) B[(size_t)rr * HD + n] = f2bf(acc[r]);
    }
  }
}

__device__ __forceinline__ void stage_w(const u16* __restrict__ Wt, u16* sw, int t) {
  const uint32_t* src = (const uint32_t*)Wt;
  uint32_t* dst = (uint32_t*)sw;
#pragma unroll
  for (int k = 0; k < 32; ++k) {
    int q = t + k * 256;
    int r = q >> 6;
    int u = q & 63;
    dst[r * 68 + u] = src[r * 64 + u];
  }
}

// layer-0 GEMM with fused h0 construction: reads x[N,64] fp32 directly.
// h0[n][f] = f<64 ? nan_to_num(x[n][f]) : isnan(x[n][f-64])
__global__ __launch_bounds__(256)
void gemm0_k(const float* __restrict__ x, const u16* __restrict__ Wt,
             u16* __restrict__ B, int N) {
  __shared__ u16 sw[128 * 136];
  const int t = threadIdx.x;
  stage_w(Wt, sw, t);
  __syncthreads();
  const int w = t >> 6;
  const int lane = t & 63;
  const int m = lane & 15;
  const int qd = lane >> 4;
  const int arow = blockIdx.x * 64 + w * 16 + m;
  short8 afr[4];
  if (arow < N) {
    const float* xp = x + (size_t)arow * 64;
    float v0[8], v1[8];
    *(float4*)&v0[0] = *(const float4*)(xp + 8 * qd);
    *(float4*)&v0[4] = *(const float4*)(xp + 8 * qd + 4);
    *(float4*)&v1[0] = *(const float4*)(xp + 32 + 8 * qd);
    *(float4*)&v1[4] = *(const float4*)(xp + 32 + 8 * qd + 4);
#pragma unroll
    for (int j = 0; j < 8; ++j) {
      bool n0 = isnan(v0[j]), n1 = isnan(v1[j]);
      afr[0][j] = (short)f2bf(n0 ? 0.f : v0[j]);
      afr[1][j] = (short)f2bf(n1 ? 0.f : v1[j]);
      afr[2][j] = (short)(n0 ? 0x3F80 : 0);
      afr[3][j] = (short)(n1 ? 0x3F80 : 0);
    }
  } else {
    short8 z = {0, 0, 0, 0, 0, 0, 0, 0};
#pragma unroll
    for (int s = 0; s < 4; ++s) afr[s] = z;
  }
  const int orow = blockIdx.x * 64 + w * 16 + qd * 4;
  gemm_core(sw, afr, m, qd, orow, B, N);
}

// generic GEMM: B = A @ W, A bf16
__global__ __launch_bounds__(256)
void gemm_k(const u16* __restrict__ A, const u16* __restrict__ Wt,
            u16* __restrict__ B, int N) {
  __shared__ u16 sw[128 * 136];
  const int t = threadIdx.x;
  stage_w(Wt, sw, t);
  __syncthreads();
  const int w = t >> 6;
  const int lane = t & 63;
  const int m = lane & 15;
  const int qd = lane >> 4;
  const int arow = blockIdx.x * 64 + w * 16 + m;
  short8 afr[4];
  if (arow < N) {
    const short8* ap = (const short8*)(A + (size_t)arow * HD);
#pragma unroll
    for (int s = 0; s < 4; ++s) afr[s] = ap[4 * s + qd];
  } else {
    short8 z = {0, 0, 0, 0, 0, 0, 0, 0};
#pragma unroll
    for (int s = 0; s < 4; ++s) afr[s] = z;
  }
  const int orow = blockIdx.x * 64 + w * 16 + qd * 4;
  gemm_core(sw, afr, m, qd, orow, B, N);
}

// Fused: A[n] = BN?ReLU( dinv[n]^2*B[n] + bias + sum_in norm*B[row] )
// 16 lanes/node, 16B short8 gathers, edge loop unrolled x4 for MLP.
__global__ __launch_bounds__(256)
void aggregate_k(const int* __restrict__ offs, const int2* __restrict__ csc,
                 const u16* __restrict__ B, const float* __restrict__ dinv,
                 const float* __restrict__ bias, const float* __restrict__ gamma,
                 const float* __restrict__ beta, const float* __restrict__ mean,
                 const float* __restrict__ var, int do_bn,
                 u16* __restrict__ A, int N) {
  int tid = blockIdx.x * 256 + threadIdx.x;
  int n = tid >> 4;
  if (n >= N) return;
  int f8 = (tid & 15) << 3;
  float d = dinv[n];
  float d2 = d * d;
  float acc[8];
  short8 bu = *(const short8*)(B + (size_t)n * HD + f8);
  float4 bi0 = *(const float4*)(bias + f8);
  float4 bi1 = *(const float4*)(bias + f8 + 4);
#pragma unroll
  for (int j = 0; j < 8; ++j) acc[j] = d2 * bf2f((u16)bu[j]);
  acc[0] += bi0.x; acc[1] += bi0.y; acc[2] += bi0.z; acc[3] += bi0.w;
  acc[4] += bi1.x; acc[5] += bi1.y; acc[6] += bi1.z; acc[7] += bi1.w;

  int p = offs[n], pe = offs[n + 1];
  for (; p + 3 < pe; p += 4) {
    int2 e0 = csc[p], e1 = csc[p + 1], e2 = csc[p + 2], e3 = csc[p + 3];
    short8 h0 = *(const short8*)(B + (size_t)e0.x * HD + f8);
    short8 h1 = *(const short8*)(B + (size_t)e1.x * HD + f8);
    short8 h2 = *(const short8*)(B + (size_t)e2.x * HD + f8);
    short8 h3 = *(const short8*)(B + (size_t)e3.x * HD + f8);
    float w0 = __int_as_float(e0.y), w1 = __int_as_float(e1.y);
    float w2 = __int_as_float(e2.y), w3 = __int_as_float(e3.y);
#pragma unroll
    for (int j = 0; j < 8; ++j) {
      acc[j] += w0 * bf2f((u16)h0[j]) + w1 * bf2f((u16)h1[j])
              + w2 * bf2f((u16)h2[j]) + w3 * bf2f((u16)h3[j]);
    }
  }
  for (; p < pe; ++p) {
    int2 e0 = csc[p];
    float w0 = __int_as_float(e0.y);
    short8 h0 = *(const short8*)(B + (size_t)e0.x * HD + f8);
#pragma unroll
    for (int j = 0; j < 8; ++j) acc[j] += w0 * bf2f((u16)h0[j]);
  }
  if (do_bn) {
#pragma unroll
    for (int j = 0; j < 8; ++j) {
      float s = gamma[f8 + j] * rsqrtf(var[f8 + j] + 1e-5f);
      float v = (acc[j] - mean[f8 + j]) * s + beta[f8 + j];
      acc[j] = v > 0.f ? v : 0.f;
    }
  }
  short8 o;
#pragma unroll
  for (int j = 0; j < 8; ++j) o[j] = (short)f2bf(acc[j]);
  *(short8*)(A + (size_t)n * HD + f8) = o;
}

__device__ __forceinline__ int seg_lower_bound(const int* b32, int N, int b) {
  int lo = 0, hi = N;
  while (lo < hi) {
    int mid = (lo + hi) >> 1;
    if (b32[mid] < b) lo = mid + 1; else hi = mid;
  }
  return lo;
}

// two-stage mean pool, stage 1 (bf16 input); segment bounds found inline
__global__ __launch_bounds__(128)
void pool1_k(const u16* __restrict__ A, const int* __restrict__ b32,
             float* __restrict__ sums, int N) {
  __shared__ int sb[2];
  int b = blockIdx.y;
  if (threadIdx.x == 0) sb[0] = seg_lower_bound(b32, N, b);
  if (threadIdx.x == 1) sb[1] = seg_lower_bound(b32, N, b + 1);
  __syncthreads();
  int s = sb[0], e = sb[1];
  int len = e - s;
  if (len <= 0) return;
  int nch = gridDim.x;
  int ch = (len + nch - 1) / nch;
  int lo = s + blockIdx.x * ch;
  int hi = lo + ch; if (hi > e) hi = e;
  if (lo >= hi) return;
  int j = threadIdx.x;
  float a0 = 0.f, a1 = 0.f, a2 = 0.f, a3 = 0.f;
  int n = lo;
  for (; n + 3 < hi; n += 4) {
    a0 += bf2f(A[(size_t)(n + 0) * HD + j]);
    a1 += bf2f(A[(size_t)(n + 1) * HD + j]);
    a2 += bf2f(A[(size_t)(n + 2) * HD + j]);
    a3 += bf2f(A[(size_t)(n + 3) * HD + j]);
  }
  for (; n < hi; ++n) a0 += bf2f(A[(size_t)n * HD + j]);
  unsafeAtomicAdd(&sums[b * HD + j], (a0 + a1) + (a2 + a3));
}

// out = gelu((sums/cnt)@mW1+mb1) @ mW2 + mb2
__global__ __launch_bounds__(128)
void mlp_k(const float* __restrict__ sums, const int* __restrict__ b32,
           const float* __restrict__ mW1, const float* __restrict__ mb1,
           const float* __restrict__ mW2, const float* __restrict__ mb2,
           float* __restrict__ out, int N) {
  __shared__ float sg[128];
  __shared__ float st[128];
  __shared__ int sb[2];
  int b = blockIdx.x, j = threadIdx.x;
  if (j == 0) sb[0] = seg_lower_bound(b32, N, b);
  if (j == 1) sb[1] = seg_lower_bound(b32, N, b + 1);
  __syncthreads();
  int cnt = sb[1] - sb[0];
  float inv = 1.0f / (float)(cnt > 0 ? cnt : 1);
  sg[j] = sums[b * HD + j] * inv;
  __syncthreads();
  float s = mb1[j];
#pragma unroll 4
  for (int i = 0; i < 128; ++i) s += sg[i] * mW1[i * 128 + j];
  float ge = 0.5f * s * (1.0f + erff(s * 0.70710678118654752f));
  st[j] = ge;
  __syncthreads();
  if (j < OUTD) {
    float o = mb2[j];
#pragma unroll 4
    for (int k = 0; k < 128; ++k) o += st[k] * mW2[k * OUTD + j];
    out[b * OUTD + j] = o;
  }
}

// ---------------------------------------------------------------- launch
extern "C" void kernel_launch(void* const* d_in, const int* in_sizes, int n_in,
                              void* d_out, int out_size, void* d_ws, size_t ws_size,
                              hipStream_t stream) {
  const float* x   = (const float*)d_in[0];
  const int* ei    = (const int*)d_in[1];
  const float* ea  = (const float*)d_in[2];
  const int* bt    = (const int*)d_in[3];
  const float* W0  = (const float*)d_in[4];
  const float* b0  = (const float*)d_in[5];
  const float* W1  = (const float*)d_in[6];
  const float* b1  = (const float*)d_in[7];
  const float* W2  = (const float*)d_in[8];
  const float* b2  = (const float*)d_in[9];
  const float* bng = (const float*)d_in[10];
  const float* bnb = (const float*)d_in[11];
  const float* bnm = (const float*)d_in[12];
  const float* bnv = (const float*)d_in[13];
  const float* mW1 = (const float*)d_in[14];
  const float* mb1 = (const float*)d_in[15];
  const float* mW2 = (const float*)d_in[16];
  const float* mb2 = (const float*)d_in[17];
  float* out = (float*)d_out;

  const int N = in_sizes[0] / 64;      // 50000
  const int E = in_sizes[2];           // 800000

  char* ws = (char*)d_ws;
  size_t NB2 = (size_t)N * HD * 2;     // bf16 feature buffer
  u16* A       = (u16*)(ws);
  u16* B       = (u16*)(ws + NB2);
  char* q      = ws + 2 * NB2;
  u16* Wt      = (u16*)q;              q += (size_t)3 * HD * HD * 2;
  int2* csc    = (int2*)q;             q += (size_t)E * 8;
  int2* eidx   = (int2*)q;             q += (size_t)E * 8;
  int*  rank   = (int*)q;              q += (size_t)E * 4;
  float* dinv  = (float*)q;            q += (size_t)N * 4;
  int*   cntR  = (int*)q;              q += (size_t)NR * N * 4;
  int*   cursR = (int*)q;              q += (size_t)NR * N * 4;
  int*   offs  = (int*)q;              q += (size_t)(N + 2) * 4;
  int*   b32   = (int*)q;              q += (size_t)N * 4;
  int*   bsum  = (int*)q;              q += 64 * 4;
  float* sums  = (float*)q;            q += GD * HD * 4;

  dim3 blk(256);
  int gE  = (E + 255) / 256;
  int gN  = (N + 255) / 256;
  int nb1024 = (N + 1023) / 1024;

  hipMemsetAsync(cntR, 0, (size_t)NR * N * 4, stream);
  hipMemsetAsync(sums, 0, (size_t)GD * HD * 4, stream);
  convert_count_k<<<gE, blk, 0, stream>>>(ei, bt, eidx, b32, cntR, rank, E, N);
  scan1_k<<<nb1024, 1024, 0, stream>>>(cntR, offs, bsum, N, N);
  scan2_k<<<1, 64, 0, stream>>>(bsum, nb1024);
  scan3_k<<<gN, blk, 0, stream>>>(offs, bsum, N, E);
  cursR_k<<<gN, blk, 0, stream>>>(offs, cntR, cursR, N);
  fill_k<<<gE, blk, 0, stream>>>(eidx, ea, cursR, rank, csc, E, N);
  deg_k<<<gN, blk, 0, stream>>>(offs, csc, dinv, N);
  normcsc_k<<<gN, blk, 0, stream>>>(offs, csc, dinv, N);
  convw3_k<<<(3 * HD * HD + 255) / 256, blk, 0, stream>>>(W0, W1, W2, Wt);

  int gGemm = (N + 63) / 64;
  int gAgg  = (N * 16 + 255) / 256;

  // layer 0 (h0 construction fused into the GEMM A-fragment load)
  gemm0_k<<<gGemm, 256, 0, stream>>>(x, Wt, B, N);
  aggregate_k<<<gAgg, blk, 0, stream>>>(offs, csc, B, dinv, b0,
                                        bng, bnb, bnm, bnv, 1, A, N);
  // layer 1
  gemm_k<<<gGemm, 256, 0, stream>>>(A, Wt + HD * HD, B, N);
  aggregate_k<<<gAgg, blk, 0, stream>>>(offs, csc, B, dinv, b1,
                                        bng, bnb, bnm, bnv, 1, A, N);
  // layer 2 (no bn/relu)
  gemm_k<<<gGemm, 256, 0, stream>>>(A, Wt + 2 * HD * HD, B, N);
  aggregate_k<<<gAgg, blk, 0, stream>>>(offs, csc, B, dinv, b2,
                                        bng, bnb, bnm, bnv, 0, A, N);

  dim3 pgrid(16, GD);
  pool1_k<<<pgrid, 128, 0, stream>>>(A, b32, sums, N);
  mlp_k<<<GD, 128, 0, stream>>>(sums, b32, mW1, mb1, mW2, mb2, out, N);
}

// Round 11
// 333.756 us; speedup vs baseline: 1.2565x; 1.0125x over previous
//
#include <hip/hip_runtime.h>
#include <hip/hip_bf16.h>
#include <stdint.h>

#define HD 128
#define GD 64
#define OUTD 16
#define NR 16   // atomic privatization replicas

typedef unsigned short u16;
typedef __attribute__((ext_vector_type(8))) short short8;
typedef __attribute__((ext_vector_type(4))) float f32x4;

__device__ __forceinline__ float bf2f(u16 u) {
  union { uint32_t i; float f; } v; v.i = ((uint32_t)u) << 16; return v.f;
}
__device__ __forceinline__ u16 f2bf(float f) {
  union { __hip_bfloat16 h; u16 u; } v; v.h = __float2bfloat16(f); return v.u;
}

// Fused: layout-detect + index convert + batch convert + privatized count
// producing per-edge rank.  k = blockIdx & (NR-1); fill_k MUST use same mapping.
__global__ __launch_bounds__(256)
void convert_count_k(const int* __restrict__ ei, const int* __restrict__ bt,
                     int2* __restrict__ eidx, int* __restrict__ b32,
                     int* __restrict__ cntR, int* __restrict__ rank,
                     int E, int N) {
  __shared__ int s_is64;
  if (threadIdx.x == 0) {
    int all0 = 1;
    for (int k = 1; k < 128; k += 2) all0 &= (ei[k] == 0);
    s_is64 = all0;
  }
  __syncthreads();
  int is64 = s_is64;
  int i = blockIdx.x * 256 + threadIdx.x;
  if (i < E) {
    int r = is64 ? ei[2 * i] : ei[i];
    int c = is64 ? ei[2 * (E + i)] : ei[E + i];
    r = (r < 0) ? 0 : (r >= N ? N - 1 : r);
    c = (c < 0) ? 0 : (c >= N ? N - 1 : c);
    eidx[i] = make_int2(r, c);
    int k = blockIdx.x & (NR - 1);
    rank[i] = atomicAdd(&cntR[k * N + c], 1);
  }
  if (i < N) {
    int v = is64 ? bt[2 * i] : bt[i];
    b32[i] = (v < 0) ? 0 : (v >= GD ? GD - 1 : v);
  }
}

// ---- scan; scan1 sums the NR replicas inline
__global__ void scan1_k(const int* __restrict__ cntR, int* __restrict__ offs,
                        int* __restrict__ bsum, int Np, int N) {
  __shared__ int s[1024];
  int i = blockIdx.x * 1024 + threadIdx.x;
  int v = 0;
  if (i < Np) {
#pragma unroll
    for (int k = 0; k < NR; ++k) v += cntR[k * N + i];
  }
  s[threadIdx.x] = v;
  __syncthreads();
  for (int off = 1; off < 1024; off <<= 1) {
    int t = (threadIdx.x >= off) ? s[threadIdx.x - off] : 0;
    __syncthreads();
    s[threadIdx.x] += t;
    __syncthreads();
  }
  if (i < Np) offs[i] = s[threadIdx.x] - v;
  if (threadIdx.x == 1023) bsum[blockIdx.x] = s[1023];
}
__global__ void scan2_k(int* bsum, int nb) {
  if (threadIdx.x == 0 && blockIdx.x == 0) {
    int sum = 0;
    for (int i = 0; i < nb; ++i) { int v = bsum[i]; bsum[i] = sum; sum += v; }
  }
}
// fused: finalize offs (+bsum), emit per-replica cursor bases, offs[N]=E
__global__ void scan3curs_k(int* __restrict__ offs, const int* __restrict__ bsum,
                            const int* __restrict__ cntR, int* __restrict__ cursR,
                            int Np, int E, int N) {
  int n = blockIdx.x * 256 + threadIdx.x;
  if (n < Np) {
    int o = offs[n] + bsum[n >> 10];
    offs[n] = o;
    int run = o;
#pragma unroll
    for (int k = 0; k < NR; ++k) { cursR[k * N + n] = run; run += cntR[k * N + n]; }
  }
  if (n == 0) offs[Np] = E;
}

// fill CSC — atomic-free: p = cursR[k][col] + rank[e]; one 8B scattered store.
// csc[p] = {row, bits(|w|)}  (|w| stays raw; dinv factored into gemm epilogue)
__global__ __launch_bounds__(256)
void fill_k(const int2* __restrict__ eidx, const float* __restrict__ ea,
            const int* __restrict__ cursR, const int* __restrict__ rank,
            int2* __restrict__ csc, int E, int N) {
  int e = blockIdx.x * 256 + threadIdx.x;
  if (e >= E) return;
  int k = blockIdx.x & (NR - 1);
  int2 rc = eidx[e];
  float a = ea[e];
  float w = isnan(a) ? 0.f : fabsf(a);
  int p = cursR[k * N + rc.y] + rank[e];
  csc[p] = make_int2(rc.x, __float_as_int(w));
}

// dinv[n] = rsqrt(sum of in-weights + 1)
__global__ void deg_k(const int* __restrict__ offs, const int2* __restrict__ csc,
                      float* __restrict__ dinv, int N) {
  int n = blockIdx.x * 256 + threadIdx.x;
  if (n >= N) return;
  int p = offs[n], pe = offs[n + 1];
  float s = 0.f;
  for (; p < pe; ++p) s += __int_as_float(csc[p].y);
  dinv[n] = rsqrtf(s + 1.0f);
}

// transpose+convert all 3 weights: Wt[l][n][k] = bf16(W_l[k][n])
__global__ void convw3_k(const float* __restrict__ W0, const float* __restrict__ W1,
                         const float* __restrict__ W2, u16* __restrict__ Wt) {
  int i = blockIdx.x * 256 + threadIdx.x;
  if (i >= 3 * HD * HD) return;
  int l = i / (HD * HD);
  int r = i - l * (HD * HD);
  int n = r >> 7, k = r & 127;
  const float* W = (l == 0) ? W0 : (l == 1) ? W1 : W2;
  Wt[i] = f2bf(W[k * HD + n]);
}

// ---- shared MFMA core: C-tile = dinv[row] * (A@W) rows, bf16 store
__device__ __forceinline__ void gemm_core(const u16* sw, const short8* afr,
                                          int m, int qd, int orow,
                                          const float* __restrict__ dinv,
                                          u16* __restrict__ B, int N) {
  float dr[4];
#pragma unroll
  for (int r = 0; r < 4; ++r) dr[r] = (orow + r < N) ? dinv[orow + r] : 0.f;
#pragma unroll
  for (int c = 0; c < 8; ++c) {
    f32x4 acc = {0.f, 0.f, 0.f, 0.f};
    const int n = c * 16 + m;
#pragma unroll
    for (int s = 0; s < 4; ++s) {
      short8 bfr = *(const short8*)(sw + n * 136 + 32 * s + 8 * qd);
      acc = __builtin_amdgcn_mfma_f32_16x16x32_bf16(afr[s], bfr, acc, 0, 0, 0);
    }
#pragma unroll
    for (int r = 0; r < 4; ++r) {
      int rr = orow + r;
      if (rr < N) B[(size_t)rr * HD + n] = f2bf(dr[r] * acc[r]);
    }
  }
}

__device__ __forceinline__ void stage_w(const u16* __restrict__ Wt, u16* sw, int t) {
  const uint32_t* src = (const uint32_t*)Wt;
  uint32_t* dst = (uint32_t*)sw;
#pragma unroll
  for (int k = 0; k < 32; ++k) {
    int q = t + k * 256;
    int r = q >> 6;
    int u = q & 63;
    dst[r * 68 + u] = src[r * 64 + u];
  }
}

// layer-0 GEMM with fused h0 construction: reads x[N,64] fp32 directly.
__global__ __launch_bounds__(256)
void gemm0_k(const float* __restrict__ x, const u16* __restrict__ Wt,
             const float* __restrict__ dinv, u16* __restrict__ B, int N) {
  __shared__ u16 sw[128 * 136];
  const int t = threadIdx.x;
  stage_w(Wt, sw, t);
  __syncthreads();
  const int w = t >> 6;
  const int lane = t & 63;
  const int m = lane & 15;
  const int qd = lane >> 4;
  const int arow = blockIdx.x * 64 + w * 16 + m;
  short8 afr[4];
  if (arow < N) {
    const float* xp = x + (size_t)arow * 64;
    float v0[8], v1[8];
    *(float4*)&v0[0] = *(const float4*)(xp + 8 * qd);
    *(float4*)&v0[4] = *(const float4*)(xp + 8 * qd + 4);
    *(float4*)&v1[0] = *(const float4*)(xp + 32 + 8 * qd);
    *(float4*)&v1[4] = *(const float4*)(xp + 32 + 8 * qd + 4);
#pragma unroll
    for (int j = 0; j < 8; ++j) {
      bool n0 = isnan(v0[j]), n1 = isnan(v1[j]);
      afr[0][j] = (short)f2bf(n0 ? 0.f : v0[j]);
      afr[1][j] = (short)f2bf(n1 ? 0.f : v1[j]);
      afr[2][j] = (short)(n0 ? 0x3F80 : 0);
      afr[3][j] = (short)(n1 ? 0x3F80 : 0);
    }
  } else {
    short8 z = {0, 0, 0, 0, 0, 0, 0, 0};
#pragma unroll
    for (int s = 0; s < 4; ++s) afr[s] = z;
  }
  const int orow = blockIdx.x * 64 + w * 16 + qd * 4;
  gemm_core(sw, afr, m, qd, orow, dinv, B, N);
}

// generic GEMM: B = dinv-scaled rows of (A @ W), A bf16
__global__ __launch_bounds__(256)
void gemm_k(const u16* __restrict__ A, const u16* __restrict__ Wt,
            const float* __restrict__ dinv, u16* __restrict__ B, int N) {
  __shared__ u16 sw[128 * 136];
  const int t = threadIdx.x;
  stage_w(Wt, sw, t);
  __syncthreads();
  const int w = t >> 6;
  const int lane = t & 63;
  const int m = lane & 15;
  const int qd = lane >> 4;
  const int arow = blockIdx.x * 64 + w * 16 + m;
  short8 afr[4];
  if (arow < N) {
    const short8* ap = (const short8*)(A + (size_t)arow * HD);
#pragma unroll
    for (int s = 0; s < 4; ++s) afr[s] = ap[4 * s + qd];
  } else {
    short8 z = {0, 0, 0, 0, 0, 0, 0, 0};
#pragma unroll
    for (int s = 0; s < 4; ++s) afr[s] = z;
  }
  const int orow = blockIdx.x * 64 + w * 16 + qd * 4;
  gemm_core(sw, afr, m, qd, orow, dinv, B, N);
}

// Fused: A[n] = BN?ReLU( dinv[n]*(C[n] + sum_in w*C[row]) + bias )
// C = dinv-prescaled GEMM output. 16 lanes/node, 16B gathers, unroll x8.
__global__ __launch_bounds__(256)
void aggregate_k(const int* __restrict__ offs, const int2* __restrict__ csc,
                 const u16* __restrict__ B, const float* __restrict__ dinv,
                 const float* __restrict__ bias, const float* __restrict__ gamma,
                 const float* __restrict__ beta, const float* __restrict__ mean,
                 const float* __restrict__ var, int do_bn,
                 u16* __restrict__ A, int N) {
  int tid = blockIdx.x * 256 + threadIdx.x;
  int n = tid >> 4;
  if (n >= N) return;
  int f8 = (tid & 15) << 3;
  float acc[8];
  short8 bu = *(const short8*)(B + (size_t)n * HD + f8);
#pragma unroll
  for (int j = 0; j < 8; ++j) acc[j] = bf2f((u16)bu[j]);   // self term C[n]

  int p = offs[n], pe = offs[n + 1];
  for (; p + 7 < pe; p += 8) {
    int2 e[8];
    short8 h[8];
#pragma unroll
    for (int u = 0; u < 8; ++u) e[u] = csc[p + u];
#pragma unroll
    for (int u = 0; u < 8; ++u) h[u] = *(const short8*)(B + (size_t)e[u].x * HD + f8);
#pragma unroll
    for (int u = 0; u < 8; ++u) {
      float w = __int_as_float(e[u].y);
#pragma unroll
      for (int j = 0; j < 8; ++j) acc[j] += w * bf2f((u16)h[u][j]);
    }
  }
  for (; p + 1 < pe; p += 2) {
    int2 e0 = csc[p], e1 = csc[p + 1];
    short8 h0 = *(const short8*)(B + (size_t)e0.x * HD + f8);
    short8 h1 = *(const short8*)(B + (size_t)e1.x * HD + f8);
    float w0 = __int_as_float(e0.y), w1 = __int_as_float(e1.y);
#pragma unroll
    for (int j = 0; j < 8; ++j)
      acc[j] += w0 * bf2f((u16)h0[j]) + w1 * bf2f((u16)h1[j]);
  }
  if (p < pe) {
    int2 e0 = csc[p];
    float w0 = __int_as_float(e0.y);
    short8 h0 = *(const short8*)(B + (size_t)e0.x * HD + f8);
#pragma unroll
    for (int j = 0; j < 8; ++j) acc[j] += w0 * bf2f((u16)h0[j]);
  }
  float dn = dinv[n];
#pragma unroll
  for (int j = 0; j < 8; ++j) acc[j] = dn * acc[j] + bias[f8 + j];
  if (do_bn) {
#pragma unroll
    for (int j = 0; j < 8; ++j) {
      float s = gamma[f8 + j] * rsqrtf(var[f8 + j] + 1e-5f);
      float v = (acc[j] - mean[f8 + j]) * s + beta[f8 + j];
      acc[j] = v > 0.f ? v : 0.f;
    }
  }
  short8 o;
#pragma unroll
  for (int j = 0; j < 8; ++j) o[j] = (short)f2bf(acc[j]);
  *(short8*)(A + (size_t)n * HD + f8) = o;
}

__device__ __forceinline__ int seg_lower_bound(const int* b32, int N, int b) {
  int lo = 0, hi = N;
  while (lo < hi) {
    int mid = (lo + hi) >> 1;
    if (b32[mid] < b) lo = mid + 1; else hi = mid;
  }
  return lo;
}

// two-stage mean pool, stage 1 (bf16 input); segment bounds found inline
__global__ __launch_bounds__(128)
void pool1_k(const u16* __restrict__ A, const int* __restrict__ b32,
             float* __restrict__ sums, int N) {
  __shared__ int sb[2];
  int b = blockIdx.y;
  if (threadIdx.x == 0) sb[0] = seg_lower_bound(b32, N, b);
  if (threadIdx.x == 1) sb[1] = seg_lower_bound(b32, N, b + 1);
  __syncthreads();
  int s = sb[0], e = sb[1];
  int len = e - s;
  if (len <= 0) return;
  int nch = gridDim.x;
  int ch = (len + nch - 1) / nch;
  int lo = s + blockIdx.x * ch;
  int hi = lo + ch; if (hi > e) hi = e;
  if (lo >= hi) return;
  int j = threadIdx.x;
  float a0 = 0.f, a1 = 0.f, a2 = 0.f, a3 = 0.f;
  int n = lo;
  for (; n + 3 < hi; n += 4) {
    a0 += bf2f(A[(size_t)(n + 0) * HD + j]);
    a1 += bf2f(A[(size_t)(n + 1) * HD + j]);
    a2 += bf2f(A[(size_t)(n + 2) * HD + j]);
    a3 += bf2f(A[(size_t)(n + 3) * HD + j]);
  }
  for (; n < hi; ++n) a0 += bf2f(A[(size_t)n * HD + j]);
  unsafeAtomicAdd(&sums[b * HD + j], (a0 + a1) + (a2 + a3));
}

// out = gelu((sums/cnt)@mW1+mb1) @ mW2 + mb2
__global__ __launch_bounds__(128)
void mlp_k(const float* __restrict__ sums, const int* __restrict__ b32,
           const float* __restrict__ mW1, const float* __restrict__ mb1,
           const float* __restrict__ mW2, const float* __restrict__ mb2,
           float* __restrict__ out, int N) {
  __shared__ float sg[128];
  __shared__ float st[128];
  __shared__ int sb[2];
  int b = blockIdx.x, j = threadIdx.x;
  if (j == 0) sb[0] = seg_lower_bound(b32, N, b);
  if (j == 1) sb[1] = seg_lower_bound(b32, N, b + 1);
  __syncthreads();
  int cnt = sb[1] - sb[0];
  float inv = 1.0f / (float)(cnt > 0 ? cnt : 1);
  sg[j] = sums[b * HD + j] * inv;
  __syncthreads();
  float s = mb1[j];
#pragma unroll 4
  for (int i = 0; i < 128; ++i) s += sg[i] * mW1[i * 128 + j];
  float ge = 0.5f * s * (1.0f + erff(s * 0.70710678118654752f));
  st[j] = ge;
  __syncthreads();
  if (j < OUTD) {
    float o = mb2[j];
#pragma unroll 4
    for (int k = 0; k < 128; ++k) o += st[k] * mW2[k * OUTD + j];
    out[b * OUTD + j] = o;
  }
}

// ---------------------------------------------------------------- launch
extern "C" void kernel_launch(void* const* d_in, const int* in_sizes, int n_in,
                              void* d_out, int out_size, void* d_ws, size_t ws_size,
                              hipStream_t stream) {
  const float* x   = (const float*)d_in[0];
  const int* ei    = (const int*)d_in[1];
  const float* ea  = (const float*)d_in[2];
  const int* bt    = (const int*)d_in[3];
  const float* W0  = (const float*)d_in[4];
  const float* b0  = (const float*)d_in[5];
  const float* W1  = (const float*)d_in[6];
  const float* b1  = (const float*)d_in[7];
  const float* W2  = (const float*)d_in[8];
  const float* b2  = (const float*)d_in[9];
  const float* bng = (const float*)d_in[10];
  const float* bnb = (const float*)d_in[11];
  const float* bnm = (const float*)d_in[12];
  const float* bnv = (const float*)d_in[13];
  const float* mW1 = (const float*)d_in[14];
  const float* mb1 = (const float*)d_in[15];
  const float* mW2 = (const float*)d_in[16];
  const float* mb2 = (const float*)d_in[17];
  float* out = (float*)d_out;

  const int N = in_sizes[0] / 64;      // 50000
  const int E = in_sizes[2];           // 800000

  char* ws = (char*)d_ws;
  size_t NB2 = (size_t)N * HD * 2;     // bf16 feature buffer
  u16* A       = (u16*)(ws);
  u16* B       = (u16*)(ws + NB2);
  char* q      = ws + 2 * NB2;
  // cntR and sums contiguous -> single memset
  int*   cntR  = (int*)q;              q += (size_t)NR * N * 4;
  float* sums  = (float*)q;            q += GD * HD * 4;
  u16* Wt      = (u16*)q;              q += (size_t)3 * HD * HD * 2;
  int2* csc    = (int2*)q;             q += (size_t)E * 8;
  int2* eidx   = (int2*)q;             q += (size_t)E * 8;
  int*  rank   = (int*)q;              q += (size_t)E * 4;
  float* dinv  = (float*)q;            q += (size_t)N * 4;
  int*   cursR = (int*)q;              q += (size_t)NR * N * 4;
  int*   offs  = (int*)q;              q += (size_t)(N + 2) * 4;
  int*   b32   = (int*)q;              q += (size_t)N * 4;
  int*   bsum  = (int*)q;              q += 64 * 4;

  dim3 blk(256);
  int gE  = (E + 255) / 256;
  int gN  = (N + 255) / 256;
  int nb1024 = (N + 1023) / 1024;

  hipMemsetAsync(cntR, 0, (size_t)NR * N * 4 + (size_t)GD * HD * 4, stream);
  convert_count_k<<<gE, blk, 0, stream>>>(ei, bt, eidx, b32, cntR, rank, E, N);
  scan1_k<<<nb1024, 1024, 0, stream>>>(cntR, offs, bsum, N, N);
  scan2_k<<<1, 64, 0, stream>>>(bsum, nb1024);
  scan3curs_k<<<gN, blk, 0, stream>>>(offs, bsum, cntR, cursR, N, E, N);
  fill_k<<<gE, blk, 0, stream>>>(eidx, ea, cursR, rank, csc, E, N);
  deg_k<<<gN, blk, 0, stream>>>(offs, csc, dinv, N);
  convw3_k<<<(3 * HD * HD + 255) / 256, blk, 0, stream>>>(W0, W1, W2, Wt);

  int gGemm = (N + 63) / 64;
  int gAgg  = (N * 16 + 255) / 256;

  // layer 0 (h0 construction fused into the GEMM A-fragment load)
  gemm0_k<<<gGemm, 256, 0, stream>>>(x, Wt, dinv, B, N);
  aggregate_k<<<gAgg, blk, 0, stream>>>(offs, csc, B, dinv, b0,
                                        bng, bnb, bnm, bnv, 1, A, N);
  // layer 1
  gemm_k<<<gGemm, 256, 0, stream>>>(A, Wt + HD * HD, dinv, B, N);
  aggregate_k<<<gAgg, blk, 0, stream>>>(offs, csc, B, dinv, b1,
                                        bng, bnb, bnm, bnv, 1, A, N);
  // layer 2 (no bn/relu)
  gemm_k<<<gGemm, 256, 0, stream>>>(A, Wt + 2 * HD * HD, dinv, B, N);
  aggregate_k<<<gAgg, blk, 0, stream>>>(offs, csc, B, dinv, b2,
                                        bng, bnb, bnm, bnv, 0, A, N);

  dim3 pgrid(32, GD);
  pool1_k<<<pgrid, 128, 0, stream>>>(A, b32, sums, N);
  mlp_k<<<GD, 128, 0, stream>>>(sums, b32, mW1, mb1, mW2, mb2, out, N);
}